// Round 7
// baseline (261.334 us; speedup 1.0000x reference)
//
#include <hip/hip_runtime.h>
#include <hip/hip_bf16.h>
#include <math.h>

#define BATCH 8
#define NPTS 4096
#define CH 128
#define CTG 8                         // column strips per batch (512 cols each)
#define ROWS 128                      // rows per block (mi=2: bfrag reuse x2)
#define CHUNK 32                      // columns staged per pipeline step
#define NCHUNK (NPTS / (CTG * CHUNK)) // 16 chunks per block
#define NBUF 3                        // ring, staged 2 ahead

// exp(s/TEMP) = 2^(s * 10 * log2(e)). sqrt(10/ln2) is folded into the
// normalize scale so the GEMM accumulator is already the exp2 argument.
#define SQRT_TEMP_LOG2E 3.79828256f   // sqrt(14.4269504089)

typedef __attribute__((ext_vector_type(4))) float    f32x4;
typedef __attribute__((ext_vector_type(4))) int      i32x4;
typedef __attribute__((ext_vector_type(8))) short    bf16x8;
typedef __attribute__((ext_vector_type(4))) _Float16 f16x4;

typedef __attribute__((address_space(3))) unsigned int lds_uint;
typedef __attribute__((address_space(1))) const unsigned int gbl_uint;

__device__ __forceinline__ void load_lds16(const void* g, const void* l) {
    __builtin_amdgcn_global_load_lds((gbl_uint*)g, (lds_uint*)l, 16, 0, 0);
}

__device__ __forceinline__ float fast_exp2(float x) {
    return __builtin_amdgcn_exp2f(x);
}

// 16x16x16 f16 MFMA (K=16). Its A/B input layout (row=lane&15, k=quad*4+j)
// matches the C/D layout of the main 16x16x32 GEMM — chained MFMAs need no
// cross-lane data movement.
__device__ __forceinline__ f32x4 mfma16(f16x4 a, f16x4 b, f32x4 c) {
#if __has_builtin(__builtin_amdgcn_mfma_f32_16x16x16f16)
    return __builtin_amdgcn_mfma_f32_16x16x16f16(a, b, c, 0, 0, 0);
#else
    f32x4 d = c;
    asm volatile("v_mfma_f32_16x16x16_f16 %0, %1, %2, %0"
                 : "+v"(d) : "v"(a), "v"(b));
    return d;
#endif
}

// ---------------------------------------------------------------------------
// Kernel 1: one-pass L2-normalize, 8 threads/point (16 ch each), 4 waves/SIMD.
// ---------------------------------------------------------------------------
__global__ __launch_bounds__(256) void normalize_kernel(
    const float* __restrict__ f, __hip_bfloat16* __restrict__ vn,
    float* __restrict__ pos, float* __restrict__ neg, float* __restrict__ out)
{
    int idx = blockIdx.x * 256 + threadIdx.x;   // 0 .. 262143
    int point = idx >> 3, q = idx & 7;          // 8 threads/point, 16 ch each
    int b = point >> 12, n = point & (NPTS - 1);
    const float* base = f + (size_t)b * CH * NPTS + (size_t)(q * 16) * NPTS + n;

    float x[16];
    float ss = 0.0f;
    #pragma unroll
    for (int c = 0; c < 16; c++) {
        x[c] = base[(size_t)c * NPTS];
        ss += x[c] * x[c];
    }
    ss += __shfl_xor(ss, 1);
    ss += __shfl_xor(ss, 2);
    ss += __shfl_xor(ss, 4);    // 8 lanes of one point share ss
    float scale = SQRT_TEMP_LOG2E / fmaxf(sqrtf(ss), 1e-12f);

    __hip_bfloat16* outp = vn + (size_t)point * CH + q * 16;
    #pragma unroll
    for (int c0 = 0; c0 < 16; c0 += 8) {
        union { __hip_bfloat16 h[8]; uint4 u; } pk;
        #pragma unroll
        for (int j = 0; j < 8; j++)
            pk.h[j] = __float2bfloat16(x[c0 + j] * scale);
        *((uint4*)(outp + c0)) = pk.u;
    }
    if (q == 0) pos[point] = 0.0f;
    else if (q == 1) neg[point] = 0.0f;
    if (idx == 0) out[0] = 0.0f;
}

// ---------------------------------------------------------------------------
// Kernel 2: persistent column-strip GEMM. R7 = R5's per-wave efficiency
// (ROWS=128, mi=2: every bfrag ds_read feeds TWO MFMAs) + R6's residency
// lever done right: CTG=8 (512-col strips) doubles the grid to 2048 blocks
// while LDS = 3x8KB + 2KB = 26.6KB allows 6 blocks/CU; launch_bounds(256,6)
// caps VGPR at 84 (measured 64 in R5's identical body shape).
//
// R6 post-mortem: ROWS=64 halved bfrag reuse and quartered per-wave
// amortization — occupancy rose 30->42% but tile REGRESSED 46->58us
// (VALUBusy up on overhead, WRITE/FETCH doubled). ILP was sold for TLP at a
// losing rate. This config keeps both: 16 main MFMA + 4 class-MFMA per body
// on 8 ds_reads, 6 resident blocks/CU, total staging bytes back to R5's
// level (half-length strips x twice the blocks).
//
// Pipeline per body (16 bodies): [ bar | setprio(1) | MFMA(chunk c, buf c%3
// -> accCUR) | setprio(0) | STAGE(chunk c+2 -> buf (c+2)%3) | EPI(chunk c-1,
// accPRV) | s_waitcnt vmcnt(2) ].
//  - read-validity: vmcnt(2) at end of body c-1 leaves only chunk c+1's 2
//    ops in flight => chunk c retired before bar(c).
//  - overwrite-safety: STAGE at body c writes buf (c+2)%3 == buf (c-1)%3,
//    whose ds_reads were lgkm-consumed before each wave reached bar(c).
//  - EXACTLY one STAGE (2 vm ops) per body; prologue correct under any
//    ordering (vmcnt(2) retires all but the newest 2 ops).
//
// Swapped operands: mfma(bfrag, afrag, acc) => acc[mi][ni] elem (lane,r) =
//   S[row0 + w*32 + mi*16 + lane15][colbase + chunk*32 + ni*16 + quad*4 + r]
// Class-GEMM epilogue (labels in [0,16)): qout[mi] elem (lane,r) =
//   q[class=quad*4+r, row=lane15] accumulated in the MFMA pipe;
//   p = q[l_row] - diag, tt = sum_k q[k] - diag.
// ---------------------------------------------------------------------------
__global__ __launch_bounds__(256, 6) void tile_kernel(
    const __hip_bfloat16* __restrict__ vn, const int* __restrict__ labels,
    float* __restrict__ pos, float* __restrict__ neg)
{
    __shared__ short lB[NBUF][CHUNK * CH];   // 3 x 8 KB ring
    __shared__ int labL[NPTS / CTG];         // 512 column labels of strip

    const int ctg = blockIdx.x, rt = blockIdx.y, b = blockIdx.z;
    const int tid = threadIdx.x;
    const int w = tid >> 6, lane = tid & 63;
    const int lane15 = lane & 15, quad = lane >> 4;

    const int row0 = rt * ROWS;
    const int colbase = ctg * (NPTS / CTG);
    const __hip_bfloat16* vb = vn + (size_t)b * NPTS * CH;
    const int* labb = labels + b * NPTS;

    // Stage one 32-col chunk -> ring buffer. XOR chunk swizzle at the global
    // source (LDS dest order is HW-fixed: wave-uniform base + lane*16B).
    // 4 waves x 2 iters x 4 rows. 0 bank conflicts (proven swizzle).
    auto stage = [&](int buf, int chunk) {
        const __hip_bfloat16* Bb = vb + (size_t)(colbase + chunk * CHUNK) * CH;
        #pragma unroll
        for (int i = 0; i < 2; i++) {
            int ldsrow = w * 8 + i * 4;             // wave-uniform
            int r = ldsrow + quad;                  // row this lane feeds
            int g = lane15 ^ (r & 15);              // swizzled global chunk
            load_lds16(Bb + (size_t)r * CH + g * 8, &lB[buf][ldsrow * CH]);
        }
    };

    // ---- prologue. Strip labels = 512 ints = 2KB: wave pairs load the two
    // halves (duplicate issue keeps per-wave vm op counts uniform = 1).
    load_lds16(labb + colbase + (w & 1) * 256 + lane * 4, &labL[(w & 1) * 256]);

    bf16x8 afrag[2][4];
    int lr[2];
    #pragma unroll
    for (int mi = 0; mi < 2; mi++) {
        const int row_l = w * 32 + mi * 16 + lane15;
        const __hip_bfloat16* Arow = vb + (size_t)(row0 + row_l) * CH;
        #pragma unroll
        for (int ks = 0; ks < 4; ks++)
            afrag[mi][ks] = *(const bf16x8*)(Arow + (ks * 4 + quad) * 8);
        lr[mi] = labb[row0 + row_l];
    }

    stage(0, 0);
    stage(1, 1);

    // Hoisted LDS byte offsets within a chunk buffer (8 VGPRs).
    int vad[2][4];
    #pragma unroll
    for (int ni = 0; ni < 2; ni++)
        #pragma unroll
        for (int ks = 0; ks < 4; ks++)
            vad[ni][ks] = (((ni * 16 + lane15) * CH) +
                           (((ks * 4 + quad) ^ lane15) << 3)) * 2;

    f32x4 qout[2] = {{0.0f, 0.0f, 0.0f, 0.0f}, {0.0f, 0.0f, 0.0f, 0.0f}};
    float ddiag[2] = {0.0f, 0.0f};
    const f32x4 zf = {0.0f, 0.0f, 0.0f, 0.0f};
    f32x4 accA[2][2], accB[2][2];

#define MFMA_PH(BUF_, ACC_)                                                   \
    {                                                                         \
        _Pragma("unroll")                                                     \
        for (int ni = 0; ni < 2; ni++) {                                      \
            bf16x8 bf = *(const bf16x8*)((const char*)(&lB[0][0]) +           \
                         (BUF_) * (CHUNK * CH * 2) + vad[ni][0]);             \
            ACC_[0][ni] = __builtin_amdgcn_mfma_f32_16x16x32_bf16(            \
                bf, afrag[0][0], zf, 0, 0, 0);                                \
            ACC_[1][ni] = __builtin_amdgcn_mfma_f32_16x16x32_bf16(            \
                bf, afrag[1][0], zf, 0, 0, 0);                                \
        }                                                                     \
        _Pragma("unroll")                                                     \
        for (int ks = 1; ks < 4; ks++) {                                      \
            _Pragma("unroll")                                                 \
            for (int ni = 0; ni < 2; ni++) {                                  \
                bf16x8 bf = *(const bf16x8*)((const char*)(&lB[0][0]) +       \
                             (BUF_) * (CHUNK * CH * 2) + vad[ni][ks]);        \
                ACC_[0][ni] = __builtin_amdgcn_mfma_f32_16x16x32_bf16(        \
                    bf, afrag[0][ks], ACC_[0][ni], 0, 0, 0);                  \
                ACC_[1][ni] = __builtin_amdgcn_mfma_f32_16x16x32_bf16(        \
                    bf, afrag[1][ks], ACC_[1][ni], 0, 0, 0);                  \
            }                                                                 \
        }                                                                     \
    }

#define EPI_PH(EC_, ACC_)                                                     \
    {                                                                         \
        _Pragma("unroll")                                                     \
        for (int ni = 0; ni < 2; ni++) {                                      \
            const i32x4 lc = *(const i32x4*)&labL[(EC_) * CHUNK + ni * 16 +   \
                                                  quad * 4];                  \
            f16x4 oh;                                                         \
            _Pragma("unroll")                                                 \
            for (int j = 0; j < 4; j++)                                       \
                oh[j] = (lc[j] == lane15) ? (_Float16)1.0f : (_Float16)0.0f;  \
            const int colblk = colbase + (EC_) * CHUNK + ni * 16;             \
            _Pragma("unroll")                                                 \
            for (int mi = 0; mi < 2; mi++) {                                  \
                f16x4 eh;                                                     \
                _Pragma("unroll")                                             \
                for (int r = 0; r < 4; r++)                                   \
                    eh[r] = (_Float16)fast_exp2(ACC_[mi][ni][r]);             \
                if (colblk == row0 + w * 32 + mi * 16) {  /* wave-uniform */  \
                    _Pragma("unroll")                                         \
                    for (int r = 0; r < 4; r++)                               \
                        if (lane15 == quad * 4 + r)                           \
                            ddiag[mi] += (float)eh[r];                        \
                }                                                             \
                qout[mi] = mfma16(oh, eh, qout[mi]);                          \
            }                                                                 \
        }                                                                     \
    }

#define BODY(C_, BUF_, CUR_, PRV_, DOEPI_)                                    \
    {                                                                         \
        __builtin_amdgcn_s_barrier();                                         \
        __builtin_amdgcn_s_setprio(1);                                        \
        MFMA_PH(BUF_, CUR_);                                                  \
        __builtin_amdgcn_s_setprio(0);                                        \
        stage(((BUF_) + 2) % 3, ((C_) + 2) & (NCHUNK - 1));                   \
        if (DOEPI_) { EPI_PH((C_) - 1, PRV_); }                               \
        asm volatile("s_waitcnt vmcnt(2)" ::: "memory");                      \
    }

    asm volatile("s_waitcnt vmcnt(2)" ::: "memory");   // chunk 0 ready
    BODY(0, 0, accA, accB, 0);
    // bodies 1..12: buf period 3, acc ping-pong period 2 -> 6-groups.
    #pragma unroll 1
    for (int c = 1; c <= 7; c += 6) {        // c = 1, 7
        BODY(c + 0, 1, accB, accA, 1);
        BODY(c + 1, 2, accA, accB, 1);
        BODY(c + 2, 0, accB, accA, 1);
        BODY(c + 3, 1, accA, accB, 1);
        BODY(c + 4, 2, accB, accA, 1);
        BODY(c + 5, 0, accA, accB, 1);
    }
    BODY(13, 1, accB, accA, 1);              // stages chunk 15 -> buf 0
    BODY(14, 2, accA, accB, 1);              // stages dead chunk 0 -> buf 1
    // body 15: buf 0, no stage / no trailing wait.
    __builtin_amdgcn_s_barrier();
    __builtin_amdgcn_s_setprio(1);
    MFMA_PH(0, accB);
    __builtin_amdgcn_s_setprio(0);
    EPI_PH(14, accA);
    EPI_PH(15, accB);

#undef BODY
#undef EPI_PH
#undef MFMA_PH

    // ---- strip done. qout[mi] elem (lane,r) = q[class=quad*4+r, row=lane15].
    #pragma unroll
    for (int mi = 0; mi < 2; mi++) {
        float p = -ddiag[mi], tt = -ddiag[mi];
        #pragma unroll
        for (int r = 0; r < 4; r++) {
            float v = qout[mi][r];
            tt += v;
            p  += (quad * 4 + r == lr[mi]) ? v : 0.0f;
        }
        p  += __shfl_xor(p, 16);   p  += __shfl_xor(p, 32);
        tt += __shfl_xor(tt, 16);  tt += __shfl_xor(tt, 32);
        if (lane < 16) {
            const int row_l = w * 32 + mi * 16 + lane15;
            atomicAdd(&pos[b * NPTS + row0 + row_l], p);
            atomicAdd(&neg[b * NPTS + row0 + row_l], tt - p);
        }
    }
}

// ---------------------------------------------------------------------------
// Kernel 3: mean of log((p+n)/p) over 32768 rows. 32 blocks x 256 threads;
// out zeroed by normalize_kernel, stream order makes the atomic safe.
// ---------------------------------------------------------------------------
__global__ __launch_bounds__(256) void finalize_kernel(
    const float* __restrict__ pos, const float* __restrict__ neg,
    float* __restrict__ out)
{
    int base = blockIdx.x * 1024 + threadIdx.x;
    float acc = 0.0f;
    #pragma unroll
    for (int k = 0; k < 4; k++) {
        int i = base + k * 256;
        float p = pos[i];
        float t = p + neg[i];
        acc += __logf(t / p);   // == -log(p / (p+n))
    }
    #pragma unroll
    for (int off = 32; off; off >>= 1) acc += __shfl_down(acc, off);
    __shared__ float red[4];
    if ((threadIdx.x & 63) == 0) red[threadIdx.x >> 6] = acc;
    __syncthreads();
    if (threadIdx.x == 0) {
        float v = red[0] + red[1] + red[2] + red[3];
        atomicAdd(out, v * (1.0f / (BATCH * NPTS)));
    }
}

extern "C" void kernel_launch(void* const* d_in, const int* in_sizes, int n_in,
                              void* d_out, int out_size, void* d_ws, size_t ws_size,
                              hipStream_t stream)
{
    const float* features = (const float*)d_in[0];
    const int*   labels   = (const int*)d_in[1];
    float*       out      = (float*)d_out;

    // Workspace: vn bf16 [8][4096][128] = 8 MB, then pos/neg fp32.
    __hip_bfloat16* vn = (__hip_bfloat16*)d_ws;
    float* pos = (float*)((char*)d_ws + (size_t)BATCH * NPTS * CH * sizeof(__hip_bfloat16));
    float* neg = pos + BATCH * NPTS;

    hipLaunchKernelGGL(normalize_kernel, dim3(BATCH * NPTS * 8 / 256), dim3(256), 0, stream,
                       features, vn, pos, neg, out);
    // 128-row x 512-col strip blocks: 8 ctg x 32 rt x 8 batches = 2048
    // blocks; 26.6KB LDS -> 6 resident blocks/CU (24 waves/CU ceiling).
    hipLaunchKernelGGL(tile_kernel, dim3(CTG, NPTS / ROWS, BATCH), dim3(256), 0, stream,
                       vn, labels, pos, neg);
    hipLaunchKernelGGL(finalize_kernel, dim3(32), dim3(256), 0, stream, pos, neg, out);
}

// Round 8
// 111.044 us; speedup vs baseline: 2.3534x; 2.3534x over previous
//
#include <hip/hip_runtime.h>
#include <hip/hip_bf16.h>
#include <math.h>

#define BATCH 8
#define NPTS 4096
#define CH 128
#define CTG 8                         // column strips per batch (512 cols each)
#define ROWS 128                      // rows per block (mi=2: bfrag reuse x2)
#define CHUNK 32                      // columns staged per pipeline step
#define NCHUNK (NPTS / (CTG * CHUNK)) // 16 chunks per block
#define NBUF 3                        // ring, staged 2 ahead

// exp(s/TEMP) = 2^(s * 10 * log2(e)). sqrt(10/ln2) is folded into the
// normalize scale so the GEMM accumulator is already the exp2 argument.
#define SQRT_TEMP_LOG2E 3.79828256f   // sqrt(14.4269504089)

typedef __attribute__((ext_vector_type(4))) float    f32x4;
typedef __attribute__((ext_vector_type(4))) int      i32x4;
typedef __attribute__((ext_vector_type(8))) short    bf16x8;
typedef __attribute__((ext_vector_type(4))) _Float16 f16x4;

typedef __attribute__((address_space(3))) unsigned int lds_uint;
typedef __attribute__((address_space(1))) const unsigned int gbl_uint;

__device__ __forceinline__ void load_lds16(const void* g, const void* l) {
    __builtin_amdgcn_global_load_lds((gbl_uint*)g, (lds_uint*)l, 16, 0, 0);
}

__device__ __forceinline__ float fast_exp2(float x) {
    return __builtin_amdgcn_exp2f(x);
}

// 16x16x16 f16 MFMA (K=16). Its A/B input layout (row=lane&15, k=quad*4+j)
// matches the C/D layout of the main 16x16x32 GEMM — chained MFMAs need no
// cross-lane data movement.
__device__ __forceinline__ f32x4 mfma16(f16x4 a, f16x4 b, f32x4 c) {
#if __has_builtin(__builtin_amdgcn_mfma_f32_16x16x16f16)
    return __builtin_amdgcn_mfma_f32_16x16x16f16(a, b, c, 0, 0, 0);
#else
    f32x4 d = c;
    asm volatile("v_mfma_f32_16x16x16_f16 %0, %1, %2, %0"
                 : "+v"(d) : "v"(a), "v"(b));
    return d;
#endif
}

// ---------------------------------------------------------------------------
// Kernel 1: one-pass L2-normalize, 8 threads/point (16 ch each), 4 waves/SIMD.
// ---------------------------------------------------------------------------
__global__ __launch_bounds__(256) void normalize_kernel(
    const float* __restrict__ f, __hip_bfloat16* __restrict__ vn,
    float* __restrict__ pos, float* __restrict__ neg, float* __restrict__ out)
{
    int idx = blockIdx.x * 256 + threadIdx.x;   // 0 .. 262143
    int point = idx >> 3, q = idx & 7;          // 8 threads/point, 16 ch each
    int b = point >> 12, n = point & (NPTS - 1);
    const float* base = f + (size_t)b * CH * NPTS + (size_t)(q * 16) * NPTS + n;

    float x[16];
    float ss = 0.0f;
    #pragma unroll
    for (int c = 0; c < 16; c++) {
        x[c] = base[(size_t)c * NPTS];
        ss += x[c] * x[c];
    }
    ss += __shfl_xor(ss, 1);
    ss += __shfl_xor(ss, 2);
    ss += __shfl_xor(ss, 4);    // 8 lanes of one point share ss
    float scale = SQRT_TEMP_LOG2E / fmaxf(sqrtf(ss), 1e-12f);

    __hip_bfloat16* outp = vn + (size_t)point * CH + q * 16;
    #pragma unroll
    for (int c0 = 0; c0 < 16; c0 += 8) {
        union { __hip_bfloat16 h[8]; uint4 u; } pk;
        #pragma unroll
        for (int j = 0; j < 8; j++)
            pk.h[j] = __float2bfloat16(x[c0 + j] * scale);
        *((uint4*)(outp + c0)) = pk.u;
    }
    if (q == 0) pos[point] = 0.0f;
    else if (q == 1) neg[point] = 0.0f;
    if (idx == 0) out[0] = 0.0f;
}

// ---------------------------------------------------------------------------
// Kernel 2: persistent column-strip GEMM. ROWS=128 (mi=2: every bfrag
// ds_read feeds TWO MFMAs), CTG=8 (512-col strips, 2048 blocks), NBUF=3
// (LDS 26.6KB -> 6 blocks/CU by LDS).
//
// R7 post-mortem — SPILL TRIPWIRE: __launch_bounds__(256,6) capped the
// UNIFIED VGPR+AGPR budget at 512/6~=85, but the body needs ~96-100
// (arch ~64 + acc AGPRs + afrag/qout). Compiler spilled accumulators to
// scratch: WRITE_SIZE 1MB->113MB, FETCH 21->428MB, tile 46->198us. On
// gfx950 AGPRs share the launch_bounds register budget (ISA §10) — the
// occupancy arg must respect arch+acc total. Reverted to (256,4) (cap
// 128): compiler uses ~96-100 unified -> HW permits 5 waves/SIMD; LDS
// permits 6 blocks/CU; grid 2048 = 8/CU demand => 5 resident blocks/CU
// (vs R5's grid-pinned 4). That residency bump is this round's only lever;
// everything else is byte-identical to R5's proven 46us body shape.
//
// Pipeline per body (16 bodies): [ bar | setprio(1) | MFMA(chunk c, buf c%3
// -> accCUR) | setprio(0) | STAGE(chunk c+2 -> buf (c+2)%3) | EPI(chunk c-1,
// accPRV) | s_waitcnt vmcnt(2) ].
//  - read-validity: vmcnt(2) at end of body c-1 leaves only chunk c+1's 2
//    ops in flight => chunk c retired before bar(c).
//  - overwrite-safety: STAGE at body c writes buf (c+2)%3 == buf (c-1)%3,
//    whose ds_reads were lgkm-consumed before each wave reached bar(c).
//  - EXACTLY one STAGE (2 vm ops) per body; prologue correct under any
//    ordering (vmcnt(2) retires all but the newest 2 ops).
//
// Swapped operands: mfma(bfrag, afrag, acc) => acc[mi][ni] elem (lane,r) =
//   S[row0 + w*32 + mi*16 + lane15][colbase + chunk*32 + ni*16 + quad*4 + r]
// Class-GEMM epilogue (labels in [0,16)): qout[mi] elem (lane,r) =
//   q[class=quad*4+r, row=lane15] accumulated in the MFMA pipe;
//   p = q[l_row] - diag, tt = sum_k q[k] - diag.
// ---------------------------------------------------------------------------
__global__ __launch_bounds__(256, 4) void tile_kernel(
    const __hip_bfloat16* __restrict__ vn, const int* __restrict__ labels,
    float* __restrict__ pos, float* __restrict__ neg)
{
    __shared__ short lB[NBUF][CHUNK * CH];   // 3 x 8 KB ring
    __shared__ int labL[NPTS / CTG];         // 512 column labels of strip

    const int ctg = blockIdx.x, rt = blockIdx.y, b = blockIdx.z;
    const int tid = threadIdx.x;
    const int w = tid >> 6, lane = tid & 63;
    const int lane15 = lane & 15, quad = lane >> 4;

    const int row0 = rt * ROWS;
    const int colbase = ctg * (NPTS / CTG);
    const __hip_bfloat16* vb = vn + (size_t)b * NPTS * CH;
    const int* labb = labels + b * NPTS;

    // Stage one 32-col chunk -> ring buffer. XOR chunk swizzle at the global
    // source (LDS dest order is HW-fixed: wave-uniform base + lane*16B).
    // 4 waves x 2 iters x 4 rows. 0 bank conflicts (proven swizzle).
    auto stage = [&](int buf, int chunk) {
        const __hip_bfloat16* Bb = vb + (size_t)(colbase + chunk * CHUNK) * CH;
        #pragma unroll
        for (int i = 0; i < 2; i++) {
            int ldsrow = w * 8 + i * 4;             // wave-uniform
            int r = ldsrow + quad;                  // row this lane feeds
            int g = lane15 ^ (r & 15);              // swizzled global chunk
            load_lds16(Bb + (size_t)r * CH + g * 8, &lB[buf][ldsrow * CH]);
        }
    };

    // ---- prologue. Strip labels = 512 ints = 2KB: wave pairs load the two
    // halves (duplicate issue keeps per-wave vm op counts uniform = 1).
    load_lds16(labb + colbase + (w & 1) * 256 + lane * 4, &labL[(w & 1) * 256]);

    bf16x8 afrag[2][4];
    int lr[2];
    #pragma unroll
    for (int mi = 0; mi < 2; mi++) {
        const int row_l = w * 32 + mi * 16 + lane15;
        const __hip_bfloat16* Arow = vb + (size_t)(row0 + row_l) * CH;
        #pragma unroll
        for (int ks = 0; ks < 4; ks++)
            afrag[mi][ks] = *(const bf16x8*)(Arow + (ks * 4 + quad) * 8);
        lr[mi] = labb[row0 + row_l];
    }

    stage(0, 0);
    stage(1, 1);

    // Hoisted LDS byte offsets within a chunk buffer (8 VGPRs).
    int vad[2][4];
    #pragma unroll
    for (int ni = 0; ni < 2; ni++)
        #pragma unroll
        for (int ks = 0; ks < 4; ks++)
            vad[ni][ks] = (((ni * 16 + lane15) * CH) +
                           (((ks * 4 + quad) ^ lane15) << 3)) * 2;

    f32x4 qout[2] = {{0.0f, 0.0f, 0.0f, 0.0f}, {0.0f, 0.0f, 0.0f, 0.0f}};
    float ddiag[2] = {0.0f, 0.0f};
    const f32x4 zf = {0.0f, 0.0f, 0.0f, 0.0f};
    f32x4 accA[2][2], accB[2][2];

#define MFMA_PH(BUF_, ACC_)                                                   \
    {                                                                         \
        _Pragma("unroll")                                                     \
        for (int ni = 0; ni < 2; ni++) {                                      \
            bf16x8 bf = *(const bf16x8*)((const char*)(&lB[0][0]) +           \
                         (BUF_) * (CHUNK * CH * 2) + vad[ni][0]);             \
            ACC_[0][ni] = __builtin_amdgcn_mfma_f32_16x16x32_bf16(            \
                bf, afrag[0][0], zf, 0, 0, 0);                                \
            ACC_[1][ni] = __builtin_amdgcn_mfma_f32_16x16x32_bf16(            \
                bf, afrag[1][0], zf, 0, 0, 0);                                \
        }                                                                     \
        _Pragma("unroll")                                                     \
        for (int ks = 1; ks < 4; ks++) {                                      \
            _Pragma("unroll")                                                 \
            for (int ni = 0; ni < 2; ni++) {                                  \
                bf16x8 bf = *(const bf16x8*)((const char*)(&lB[0][0]) +       \
                             (BUF_) * (CHUNK * CH * 2) + vad[ni][ks]);        \
                ACC_[0][ni] = __builtin_amdgcn_mfma_f32_16x16x32_bf16(        \
                    bf, afrag[0][ks], ACC_[0][ni], 0, 0, 0);                  \
                ACC_[1][ni] = __builtin_amdgcn_mfma_f32_16x16x32_bf16(        \
                    bf, afrag[1][ks], ACC_[1][ni], 0, 0, 0);                  \
            }                                                                 \
        }                                                                     \
    }

#define EPI_PH(EC_, ACC_)                                                     \
    {                                                                         \
        _Pragma("unroll")                                                     \
        for (int ni = 0; ni < 2; ni++) {                                      \
            const i32x4 lc = *(const i32x4*)&labL[(EC_) * CHUNK + ni * 16 +   \
                                                  quad * 4];                  \
            f16x4 oh;                                                         \
            _Pragma("unroll")                                                 \
            for (int j = 0; j < 4; j++)                                       \
                oh[j] = (lc[j] == lane15) ? (_Float16)1.0f : (_Float16)0.0f;  \
            const int colblk = colbase + (EC_) * CHUNK + ni * 16;             \
            _Pragma("unroll")                                                 \
            for (int mi = 0; mi < 2; mi++) {                                  \
                f16x4 eh;                                                     \
                _Pragma("unroll")                                             \
                for (int r = 0; r < 4; r++)                                   \
                    eh[r] = (_Float16)fast_exp2(ACC_[mi][ni][r]);             \
                if (colblk == row0 + w * 32 + mi * 16) {  /* wave-uniform */  \
                    _Pragma("unroll")                                         \
                    for (int r = 0; r < 4; r++)                               \
                        if (lane15 == quad * 4 + r)                           \
                            ddiag[mi] += (float)eh[r];                        \
                }                                                             \
                qout[mi] = mfma16(oh, eh, qout[mi]);                          \
            }                                                                 \
        }                                                                     \
    }

#define BODY(C_, BUF_, CUR_, PRV_, DOEPI_)                                    \
    {                                                                         \
        __builtin_amdgcn_s_barrier();                                         \
        __builtin_amdgcn_s_setprio(1);                                        \
        MFMA_PH(BUF_, CUR_);                                                  \
        __builtin_amdgcn_s_setprio(0);                                        \
        stage(((BUF_) + 2) % 3, ((C_) + 2) & (NCHUNK - 1));                   \
        if (DOEPI_) { EPI_PH((C_) - 1, PRV_); }                               \
        asm volatile("s_waitcnt vmcnt(2)" ::: "memory");                      \
    }

    asm volatile("s_waitcnt vmcnt(2)" ::: "memory");   // chunk 0 ready
    BODY(0, 0, accA, accB, 0);
    // bodies 1..12: buf period 3, acc ping-pong period 2 -> 6-groups.
    #pragma unroll 1
    for (int c = 1; c <= 7; c += 6) {        // c = 1, 7
        BODY(c + 0, 1, accB, accA, 1);
        BODY(c + 1, 2, accA, accB, 1);
        BODY(c + 2, 0, accB, accA, 1);
        BODY(c + 3, 1, accA, accB, 1);
        BODY(c + 4, 2, accB, accA, 1);
        BODY(c + 5, 0, accA, accB, 1);
    }
    BODY(13, 1, accB, accA, 1);              // stages chunk 15 -> buf 0
    BODY(14, 2, accA, accB, 1);              // stages dead chunk 0 -> buf 1
    // body 15: buf 0, no stage / no trailing wait.
    __builtin_amdgcn_s_barrier();
    __builtin_amdgcn_s_setprio(1);
    MFMA_PH(0, accB);
    __builtin_amdgcn_s_setprio(0);
    EPI_PH(14, accA);
    EPI_PH(15, accB);

#undef BODY
#undef EPI_PH
#undef MFMA_PH

    // ---- strip done. qout[mi] elem (lane,r) = q[class=quad*4+r, row=lane15].
    #pragma unroll
    for (int mi = 0; mi < 2; mi++) {
        float p = -ddiag[mi], tt = -ddiag[mi];
        #pragma unroll
        for (int r = 0; r < 4; r++) {
            float v = qout[mi][r];
            tt += v;
            p  += (quad * 4 + r == lr[mi]) ? v : 0.0f;
        }
        p  += __shfl_xor(p, 16);   p  += __shfl_xor(p, 32);
        tt += __shfl_xor(tt, 16);  tt += __shfl_xor(tt, 32);
        if (lane < 16) {
            const int row_l = w * 32 + mi * 16 + lane15;
            atomicAdd(&pos[b * NPTS + row0 + row_l], p);
            atomicAdd(&neg[b * NPTS + row0 + row_l], tt - p);
        }
    }
}

// ---------------------------------------------------------------------------
// Kernel 3: mean of log((p+n)/p) over 32768 rows. 32 blocks x 256 threads;
// out zeroed by normalize_kernel, stream order makes the atomic safe.
// ---------------------------------------------------------------------------
__global__ __launch_bounds__(256) void finalize_kernel(
    const float* __restrict__ pos, const float* __restrict__ neg,
    float* __restrict__ out)
{
    int base = blockIdx.x * 1024 + threadIdx.x;
    float acc = 0.0f;
    #pragma unroll
    for (int k = 0; k < 4; k++) {
        int i = base + k * 256;
        float p = pos[i];
        float t = p + neg[i];
        acc += __logf(t / p);   // == -log(p / (p+n))
    }
    #pragma unroll
    for (int off = 32; off; off >>= 1) acc += __shfl_down(acc, off);
    __shared__ float red[4];
    if ((threadIdx.x & 63) == 0) red[threadIdx.x >> 6] = acc;
    __syncthreads();
    if (threadIdx.x == 0) {
        float v = red[0] + red[1] + red[2] + red[3];
        atomicAdd(out, v * (1.0f / (BATCH * NPTS)));
    }
}

extern "C" void kernel_launch(void* const* d_in, const int* in_sizes, int n_in,
                              void* d_out, int out_size, void* d_ws, size_t ws_size,
                              hipStream_t stream)
{
    const float* features = (const float*)d_in[0];
    const int*   labels   = (const int*)d_in[1];
    float*       out      = (float*)d_out;

    // Workspace: vn bf16 [8][4096][128] = 8 MB, then pos/neg fp32.
    __hip_bfloat16* vn = (__hip_bfloat16*)d_ws;
    float* pos = (float*)((char*)d_ws + (size_t)BATCH * NPTS * CH * sizeof(__hip_bfloat16));
    float* neg = pos + BATCH * NPTS;

    hipLaunchKernelGGL(normalize_kernel, dim3(BATCH * NPTS * 8 / 256), dim3(256), 0, stream,
                       features, vn, pos, neg, out);
    // 128-row x 512-col strip blocks: 8 ctg x 32 rt x 8 batches = 2048
    // blocks; LDS 26.6KB / ~100 unified regs -> 5 resident blocks/CU.
    hipLaunchKernelGGL(tile_kernel, dim3(CTG, NPTS / ROWS, BATCH), dim3(256), 0, stream,
                       vn, labels, pos, neg);
    hipLaunchKernelGGL(finalize_kernel, dim3(32), dim3(256), 0, stream, pos, neg, out);
}